// Round 13
// baseline (479.066 us; speedup 1.0000x reference)
//
#include <hip/hip_runtime.h>
#include <hip/hip_bf16.h>
#include <math.h>

// Model dims
#define BB 8
#define TT 1024
#define DD 256
#define HH 512
#define NN 16
#define RR 8
#define OUT_LEN 96
#define IN_DIM 32
#define MM (BB*TT)   // 8192 rows

// scan chunking: SC=16 -> CC=64
#define SC 16
#define CC (TT/SC)   // 64

typedef unsigned short u16;
typedef unsigned int u32;
typedef __attribute__((ext_vector_type(8))) short short8;
typedef __attribute__((ext_vector_type(8))) unsigned short u16x8;
typedef __attribute__((ext_vector_type(4))) float float4v;

__device__ __forceinline__ u16 f2bf(float f) {
    __hip_bfloat16 h = __float2bfloat16(f);
    return *(u16*)&h;
}
__device__ __forceinline__ float bf2f(u16 u) {
    u32 v = ((u32)u) << 16;
    return *(float*)&v;
}

#define GLD_LDS16(src, dst) __builtin_amdgcn_global_load_lds( \
    (const __attribute__((address_space(1))) void*)(src),     \
    (__attribute__((address_space(3))) void*)(dst), 16, 0, 0)

// Raw barrier + counted vmcnt (T4).
#define SBAR()   asm volatile("s_barrier" ::: "memory")
#define VMCNT0() asm volatile("s_waitcnt vmcnt(0)" ::: "memory")
#define VMCNT2() asm volatile("s_waitcnt vmcnt(2)" ::: "memory")
#define VMCNT6() asm volatile("s_waitcnt vmcnt(6)" ::: "memory")

// ---------------------------------------------------------------------------
// Embedding + PE + layer-0 LN (blocks 0..MM-1)  |  weight bf16 cvt (rest).
// ---------------------------------------------------------------------------
__global__ __launch_bounds__(256) void embed_ln_cvt_kernel(
    const float* __restrict__ x, const float* __restrict__ emb_w,
    const float* __restrict__ emb_b,
    const float* __restrict__ g, const float* __restrict__ b,
    float* __restrict__ h, u16* __restrict__ lnout,
    const float* __restrict__ w_in, u16* __restrict__ wbf_in,
    const float* __restrict__ w_out, u16* __restrict__ wbf_out, int nw)
{
    int bid = blockIdx.x;
    if (bid >= MM) {
        int i = (bid - MM) * 256 + threadIdx.x;
        if (i < nw) wbf_in[i] = f2bf(w_in[i]);
        else        wbf_out[i - nw] = f2bf(w_out[i - nw]);
        return;
    }

    int bt = bid;
    int d  = threadIdx.x;
    int t  = bt & (TT - 1);

    __shared__ float xs[IN_DIM];
    __shared__ float red[4], red2[4];
    if (threadIdx.x < IN_DIM) xs[threadIdx.x] = x[bt * IN_DIM + threadIdx.x];
    __syncthreads();

    const float* w = emb_w + d * IN_DIM;
    float acc = emb_b[d];
#pragma unroll
    for (int i = 0; i < IN_DIM; i++) acc = fmaf(xs[i], w[i], acc);

    int i2 = d & ~1;
    float div = __expf(-(float)i2 * 0.0359778918f);   // ln(10000)/256
    float arg = (float)t * div;
    float pe = (d & 1) ? __cosf(arg) : __sinf(arg);
    float val = acc + pe;
    h[bt * DD + d] = val;

    float s = val;
#pragma unroll
    for (int o = 32; o > 0; o >>= 1) s += __shfl_down(s, o);
    int lane = d & 63, wave = d >> 6;
    if (lane == 0) red[wave] = s;
    __syncthreads();
    float mean = (red[0] + red[1] + red[2] + red[3]) * (1.0f / DD);

    float c = val - mean;
    float s2 = c * c;
#pragma unroll
    for (int o = 32; o > 0; o >>= 1) s2 += __shfl_down(s2, o);
    if (lane == 0) red2[wave] = s2;
    __syncthreads();
    float var = (red2[0] + red2[1] + red2[2] + red2[3]) * (1.0f / DD);

    lnout[bt * DD + d] = f2bf(c * rsqrtf(var + 1e-5f) * g[d] + b[d]);
}

// ---------------------------------------------------------------------------
// bf16 MFMA NT GEMM, 128x64, BK=64, dbuf + counted-vmcnt (R7/R8-validated).
// ---------------------------------------------------------------------------
template<int BM, int BN, int OUT_BF16>
__global__ __launch_bounds__(256) void gemm_bf16(
    const u16* __restrict__ A, const u16* __restrict__ B,
    void* __restrict__ Cv, int M, int N, int K, int addC)
{
    constexpr int BK = 64;
    constexpr int MT = BM / 32;
    constexpr int NT = BN / 32;
    static_assert(BM == 128 && BN == 64, "vmcnt count assumes 6 loads/thread");

    __shared__ __align__(16) u16 Al[2][8][BM][8];
    __shared__ __align__(16) u16 Bl[2][8][BN][8];

    const int tid = threadIdx.x;
    const int bm = blockIdx.y * BM;
    const int bn = blockIdx.x * BN;
    const int wid = tid >> 6, lane = tid & 63;
    const int wm = wid >> 1, wn = wid & 1;
    const int lq = lane >> 4, lm = lane & 15;

    float4v acc[MT][NT];
#pragma unroll
    for (int i = 0; i < MT; i++)
#pragma unroll
        for (int j = 0; j < NT; j++) acc[i][j] = (float4v){0.f, 0.f, 0.f, 0.f};

#pragma unroll
    for (int it = 0; it < (8 * BM) / 256; it++) {
        int c = it * 256 + tid;
        int q = c / BM, row = c % BM;
        GLD_LDS16(A + (size_t)(bm + row) * K + q * 8, &Al[0][q][row][0]);
    }
#pragma unroll
    for (int it = 0; it < (8 * BN) / 256; it++) {
        int c = it * 256 + tid;
        int q = c / BN, row = c % BN;
        GLD_LDS16(B + (size_t)(bn + row) * K + q * 8, &Bl[0][q][row][0]);
    }

    const int nt = K / BK;
    int cur = 0;
    for (int i = 0; i < nt; i++) {
        if (i + 1 < nt) {
            int nxt = cur ^ 1;
            int k1 = (i + 1) * BK;
#pragma unroll
            for (int it = 0; it < (8 * BM) / 256; it++) {
                int c = it * 256 + tid;
                int q = c / BM, row = c % BM;
                GLD_LDS16(A + (size_t)(bm + row) * K + k1 + q * 8, &Al[nxt][q][row][0]);
            }
#pragma unroll
            for (int it = 0; it < (8 * BN) / 256; it++) {
                int c = it * 256 + tid;
                int q = c / BN, row = c % BN;
                GLD_LDS16(B + (size_t)(bn + row) * K + k1 + q * 8, &Bl[nxt][q][row][0]);
            }
            VMCNT6();
        } else {
            VMCNT0();
        }
        SBAR();

        short8 af[2][MT], bf[2][NT];
#pragma unroll
        for (int kk = 0; kk < 2; kk++) {
#pragma unroll
            for (int mt = 0; mt < MT; mt++)
                af[kk][mt] = *(const short8*)&Al[cur][kk * 4 + lq][wm * (BM / 2) + mt * 16 + lm][0];
#pragma unroll
            for (int nt2 = 0; nt2 < NT; nt2++)
                bf[kk][nt2] = *(const short8*)&Bl[cur][kk * 4 + lq][wn * (BN / 2) + nt2 * 16 + lm][0];
        }

#pragma unroll
        for (int kk = 0; kk < 2; kk++)
#pragma unroll
            for (int mt = 0; mt < MT; mt++)
#pragma unroll
                for (int nt2 = 0; nt2 < NT; nt2++)
                    acc[mt][nt2] = __builtin_amdgcn_mfma_f32_16x16x32_bf16(
                        af[kk][mt], bf[kk][nt2], acc[mt][nt2], 0, 0, 0);
        SBAR();
        cur ^= 1;
    }

#pragma unroll
    for (int mt = 0; mt < MT; mt++)
#pragma unroll
        for (int nt2 = 0; nt2 < NT; nt2++) {
            int row0 = bm + wm * (BM / 2) + mt * 16 + lq * 4;
            int col  = bn + wn * (BN / 2) + nt2 * 16 + lm;
#pragma unroll
            for (int r = 0; r < 4; r++) {
                float vv = acc[mt][nt2][r];
                if (OUT_BF16) {
                    ((u16*)Cv)[(size_t)(row0 + r) * N + col] = f2bf(vv);
                } else {
                    float* cp = (float*)Cv + (size_t)(row0 + r) * N + col;
                    if (addC) vv += *cp;
                    *cp = vv;
                }
            }
        }
}

// ---------------------------------------------------------------------------
__device__ __forceinline__ float softplus_f(float s) {
    return (s > 20.0f) ? s : __logf(1.0f + __expf(s));
}

// ---------------------------------------------------------------------------
// Fused conv+SiLU+dt1 + chunk-local scan (pass 1). R7/R8-validated.
// ---------------------------------------------------------------------------
__global__ __launch_bounds__(512, 4) void conv_scan1(
    const u16* __restrict__ vbf, const float* __restrict__ cwg,
    const float* __restrict__ w1g, const float* __restrict__ b1g,
    const float* __restrict__ dt2_w, const float* __restrict__ dt2_b,
    const float* __restrict__ A_p,
    u16* __restrict__ vsb, float* __restrict__ dtr,
    u16* __restrict__ Lst, float* __restrict__ sdt)
{
    const int c = blockIdx.x;
    const int b = blockIdx.y;
    const int tid = threadIdx.x;
    const int wave = tid >> 6, lane = tid & 63;
    const int h0 = lane * 8;

    __shared__ float w1s[RR * 2 * 256];       // 16 KB dt1 weights
    __shared__ u16   a_lds[SC][HH];           // 16 KB conv+silu output (bf16)
    __shared__ float ds[SC * RR];             // 512 B dt1 output per row

#pragma unroll
    for (int i = 0; i < 2; i++) {
        int rci = wave + i * 8;               // 0..15
        int r = rci >> 1, jc = rci & 1;
        float4 wv = *(const float4*)(w1g + r * HH + lane * 8 + jc * 4);
        *(float4*)&w1s[rci * 256 + lane * 4] = wv;
    }
    __syncthreads();

    const float* wp = cwg + h0 * 3;
#pragma unroll
    for (int i = 0; i < 2; i++) {
        int tr = wave + i * 8;                // 0..15
        int t  = c * SC + tr;
        size_t m = (size_t)b * TT + t;

        const u16* vrow = vbf + m * HH + h0;
        u16x8 x0 = *(const u16x8*)vrow;
        u16x8 xm = (t > 0)      ? *(const u16x8*)(vrow - HH) : (u16x8)(0);
        u16x8 xp = (t < TT - 1) ? *(const u16x8*)(vrow + HH) : (u16x8)(0);

        float a[8];
        u16x8 o;
#pragma unroll
        for (int j = 0; j < 8; j++) {
            float s = wp[j * 3] * bf2f(xm[j]);
            s = fmaf(wp[j * 3 + 1], bf2f(x0[j]), s);
            s = fmaf(wp[j * 3 + 2], bf2f(xp[j]), s);
            s = s / (1.0f + __expf(-s));
            a[j] = s;
            o[j] = f2bf(s);
        }
        *(u16x8*)(vsb + m * HH + h0) = o;       // for fused pass2
        *(u16x8*)&a_lds[tr][h0]      = o;       // for local scan (same bf16)

        float acc[RR];
#pragma unroll
        for (int r = 0; r < RR; r++) {
            float4 wlo = *(const float4*)&w1s[(r * 2 + 0) * 256 + lane * 4];
            float4 whi = *(const float4*)&w1s[(r * 2 + 1) * 256 + lane * 4];
            float s = a[0] * wlo.x;
            s = fmaf(a[1], wlo.y, s);
            s = fmaf(a[2], wlo.z, s);
            s = fmaf(a[3], wlo.w, s);
            s = fmaf(a[4], whi.x, s);
            s = fmaf(a[5], whi.y, s);
            s = fmaf(a[6], whi.z, s);
            s = fmaf(a[7], whi.w, s);
            acc[r] = s;
        }
#pragma unroll
        for (int r = 0; r < RR; r++) {
#pragma unroll
            for (int o2 = 1; o2 < 64; o2 <<= 1) acc[r] += __shfl_xor(acc[r], o2);
        }
        if (lane == 0) {
#pragma unroll
            for (int r = 0; r < RR; r++) acc[r] = fmaxf(acc[r] + b1g[r], 0.0f);
            *(float4*)(dtr + m * RR)     = make_float4(acc[0], acc[1], acc[2], acc[3]);
            *(float4*)(dtr + m * RR + 4) = make_float4(acc[4], acc[5], acc[6], acc[7]);
#pragma unroll
            for (int r = 0; r < RR; r++) ds[tr * RR + r] = acc[r];
        }
    }
    __syncthreads();

    const int h = tid;
    float A2[NN], invA[NN], st[NN];
    const float* ap = A_p + h * NN;
#pragma unroll
    for (int n = 0; n < NN; n++) {
        float av = -__expf(ap[n]);
        A2[n] = av * 1.44269504f;
        invA[n] = 1.0f / av;
        st[n] = 0.0f;
    }
    float w2[RR];
#pragma unroll
    for (int r = 0; r < RR; r++) w2[r] = dt2_w[h * RR + r];
    float b2 = dt2_b[h];

    float xv = bf2f(a_lds[0][h]);
    float s_dt = 0.0f;
#pragma unroll 2
    for (int t = 0; t < SC; t++) {
        float xn = (t + 1 < SC) ? bf2f(a_lds[t + 1][h]) : 0.0f;
        float s = b2;
#pragma unroll
        for (int r = 0; r < RR; r++) s = fmaf(ds[t * RR + r], w2[r], s);
        float dt = softplus_f(s);
        s_dt += dt;
        float dtx = dt * xv;
#pragma unroll
        for (int n = 0; n < NN; n++) {
            float e = __builtin_amdgcn_exp2f(A2[n] * dt);
            float u = invA[n] * dtx;
            st[n] = fmaf(e, st[n] + u, -u);
        }
        xv = xn;
    }

    size_t base = (((size_t)c * BB + b) * HH + h) * NN;
    u16x8 lo, hi;
#pragma unroll
    for (int n = 0; n < 8; n++) { lo[n] = f2bf(st[n]); hi[n] = f2bf(st[n + 8]); }
    *(u16x8*)(Lst + base)     = lo;
    *(u16x8*)(Lst + base + 8) = hi;
    sdt[((size_t)c * BB + b) * HH + h] = s_dt;
}

// ---------------------------------------------------------------------------
// Wave-parallel carry (R3/R5/R7-validated). One wave per (b,h); lane = chunk.
// ---------------------------------------------------------------------------
__global__ __launch_bounds__(256) void scan_carry_par(
    const float* __restrict__ A_p, const float* __restrict__ sdt,
    u16* __restrict__ Lst)
{
    int gw   = (blockIdx.x << 2) | (threadIdx.x >> 6);
    int lane = threadIdx.x & 63;
    int b = gw >> 9;
    int h = gw & 511;

    size_t sidx = ((size_t)lane * BB + b) * HH + h;
    float sd = sdt[sidx];
    const float* ap = A_p + h * NN;
    u16x8 Llo = *(const u16x8*)(Lst + sidx * NN);
    u16x8 Lhi = *(const u16x8*)(Lst + sidx * NN + 8);
    u16x8 Elo, Ehi;
#pragma unroll
    for (int n = 0; n < NN; n++) {
        float An = -__expf(ap[n]);
        float p  = __expf(An * sd);
        float lv = bf2f((n < 8) ? Llo[n] : Lhi[n - 8]);
#pragma unroll
        for (int d2 = 1; d2 < 64; d2 <<= 1) {
            float pp = __shfl_up(p, d2);
            float pl = __shfl_up(lv, d2);
            if (lane >= d2) { lv = fmaf(pl, p, lv); p = pp * p; }
        }
        float E = __shfl_up(lv, 1);
        if (lane == 0) E = 0.0f;
        if (n < 8) Elo[n] = f2bf(E); else Ehi[n - 8] = f2bf(E);
    }
    *(u16x8*)(Lst + sidx * NN)     = Elo;
    *(u16x8*)(Lst + sidx * NN + 8) = Ehi;
}

// ---------------------------------------------------------------------------
// R22: scan-pass2 + out-projection GEMM + residual + LN, re-tiled for
// OCCUPANCY. 16 rows/block (1 chunk), grid 512, LDS ~53 KB -> 2 blocks/CU
// (16 waves/CU = 4/SIMD -- same residency as the fast R5 scan_pass2).
// Five neutral micro-opts (R19-R21) proved the old 132KB/1-block/CU variant
// was structurally latency-bound (Occupancy ~13%, VALUBusy 28%).
//   Phase S: validated single-chain scan (16 t, x from global, 1-deep pipe).
//   Phase G: BK=32, 2-deep B pipeline (2 loads/thread, vmcnt(2)); 8 waves x
//   32-col stripes, 2 MFMA/k-step. Yl swizzle involution unchanged.
// ---------------------------------------------------------------------------
__global__ __launch_bounds__(512, 4) void scan2_gemm2_ln(
    const u16* __restrict__ vsb, const float* __restrict__ dtr,
    const float* __restrict__ dt2_w, const float* __restrict__ dt2_b,
    const float* __restrict__ A_p, const float* __restrict__ D_p,
    const u16* __restrict__ carry,          // Lst (exclusive chunk prefixes)
    const u16* __restrict__ B,              // out_w bf16 [256][512]
    float* __restrict__ h,
    const float* __restrict__ g, const float* __restrict__ bb,
    u16* __restrict__ lnout, int doLN,
    const float* __restrict__ w1h, const float* __restrict__ b1h,
    const float* __restrict__ w2h, const float* __restrict__ b2h,
    float* __restrict__ outp, int doHead)
{
    const int bid = blockIdx.x;          // 0..511
    const int b   = bid >> 6;
    const int tb  = bid & 63;            // chunk index c
    const int t0  = tb * 16;
    const int bm  = bid * 16;            // global row base (b*TT + t0)

    const int tid = threadIdx.x;         // 0..511
    const int wid = tid >> 6;            // 0..7: 32-col stripe
    const int lane = tid & 63;
    const int lq = lane >> 4, lm = lane & 15;

    __shared__ __align__(16) u16 Yl[16 * 512];        // 16 KB swizzled y
    __shared__ __align__(16) u16 Bl[2][4][256][8];    // 32 KB (BK=32, 2-deep)
    __shared__ float ds[SC * RR];                      // 512 B
    __shared__ float rs[8][16], qs[8][16];             // 1 KB
    __shared__ float hn[DD], sl1[DD];                  // head scratch (2 KB)

    // B K-tile 0 (2 loads/thread) -- hides under the scan phase
#pragma unroll
    for (int it = 0; it < 2; it++) {
        int cth = it * 512 + tid;            // 0..1023
        int q = cth >> 8, row = cth & 255;   // q: k-octet 0..3
        GLD_LDS16(B + (size_t)row * 512 + q * 8, &Bl[0][q][row][0]);
    }

    // stage dt rows for this chunk
    if (tid < SC * RR) {
        int tr = tid >> 3, r = tid & 7;
        ds[tid] = dtr[((size_t)b * TT + t0 + tr) * RR + r];
    }

    const int hh = tid;

    // carry vector for this chunk
    float st[NN];
    {
        size_t cb = (((size_t)tb * BB + b) * HH + hh) * NN;
        u16x8 lo = *(const u16x8*)(carry + cb);
        u16x8 hi = *(const u16x8*)(carry + cb + 8);
#pragma unroll
        for (int n = 0; n < 8; n++) { st[n] = bf2f(lo[n]); st[n + 8] = bf2f(hi[n]); }
    }

    // per-h constants
    float A2[NN], invA[NN], Ap[NN], w2[RR];
    const float* ap = A_p + hh * NN;
#pragma unroll
    for (int n = 0; n < NN; n++) {
        float apv = ap[n]; Ap[n] = apv;
        float a = -__expf(apv);
        A2[n] = a * 1.44269504f; invA[n] = 1.0f / a;
    }
#pragma unroll
    for (int r = 0; r < RR; r++) w2[r] = dt2_w[hh * RR + r];
    float b2 = dt2_b[hh];
    float Dp = D_p[hh];
    __syncthreads();   // ds ready (drains B0 too -- it's first-issued, landed)

    // ---- Phase S: single-chain scan, x from global (validated R5 loop)
    const u16* vbase = vsb + ((size_t)b * TT + t0) * HH + hh;
    float xv = bf2f(vbase[0]);
#pragma unroll 2
    for (int t = 0; t < SC; t++) {
        float xn = (t + 1 < SC) ? bf2f(vbase[(size_t)(t + 1) * HH]) : 0.0f;
        float s = b2;
#pragma unroll
        for (int r = 0; r < RR; r++) s = fmaf(ds[t * RR + r], w2[r], s);
        float dt = softplus_f(s);
        float dtx = dt * xv;
        float acc = Dp * xv;
#pragma unroll
        for (int n = 0; n < NN; n++) {
            float e = __builtin_amdgcn_exp2f(A2[n] * dt);
            float u = invA[n] * dtx;
            st[n] = fmaf(e, st[n] + u, -u);
            acc = fmaf(st[n], Ap[n], acc);
        }
        Yl[t * 512 + (hh ^ ((t & 7) << 3))] = f2bf(acc);   // swizzled
        xv = xn;
    }
    __syncthreads();   // Yl complete; drains straggler x loads (clean vmcnt)

    // ---- Phase G: C[16x256] = Y[16x512] @ B[256x512]^T, BK=32, 2-deep
    float4v acc4[2];
    acc4[0] = (float4v){0.f, 0.f, 0.f, 0.f};
    acc4[1] = (float4v){0.f, 0.f, 0.f, 0.f};

    int cur = 0;
    for (int i = 0; i < 16; i++) {
        if (i + 1 < 16) {
            int nxt = cur ^ 1;
            int k1 = (i + 1) * 32;
#pragma unroll
            for (int it = 0; it < 2; it++) {
                int cth = it * 512 + tid;
                int q = cth >> 8, row = cth & 255;
                GLD_LDS16(B + (size_t)row * 512 + k1 + q * 8, &Bl[nxt][q][row][0]);
            }
            VMCNT2();                        // tile i landed; i+1 in flight
        } else {
            VMCNT0();
        }
        SBAR();

        int row = lm;
        int kg  = i * 4 + lq;                // k-group of 8
        short8 af = *(const short8*)&Yl[row * 512 + ((kg ^ (row & 7)) << 3)];
        short8 bf0 = *(const short8*)&Bl[cur][lq][wid * 32 + lm][0];
        short8 bf1 = *(const short8*)&Bl[cur][lq][wid * 32 + 16 + lm][0];
        acc4[0] = __builtin_amdgcn_mfma_f32_16x16x32_bf16(af, bf0, acc4[0], 0, 0, 0);
        acc4[1] = __builtin_amdgcn_mfma_f32_16x16x32_bf16(af, bf1, acc4[1], 0, 0, 0);
        SBAR();
        cur ^= 1;
    }

    // ---- Epilogue: residual + stats + LN (wave owns 16 rows x 32 cols)
    float val[4][2];
    float s1[4] = {0.f, 0.f, 0.f, 0.f}, s2[4] = {0.f, 0.f, 0.f, 0.f};
#pragma unroll
    for (int r = 0; r < 4; r++) {
        int row = bm + lq * 4 + r;
#pragma unroll
        for (int nt = 0; nt < 2; nt++) {
            int col = wid * 32 + nt * 16 + lm;
            float v = acc4[nt][r] + h[(size_t)row * DD + col];
            val[r][nt] = v;
            s1[r] += v;
            s2[r] = fmaf(v, v, s2[r]);
            h[(size_t)row * DD + col] = v;
        }
    }
#pragma unroll
    for (int r = 0; r < 4; r++) {
#pragma unroll
        for (int o = 1; o < 16; o <<= 1) {
            s1[r] += __shfl_xor(s1[r], o);
            s2[r] += __shfl_xor(s2[r], o);
        }
    }
    if (lm == 0) {
#pragma unroll
        for (int r = 0; r < 4; r++) {
            rs[wid][lq * 4 + r] = s1[r];
            qs[wid][lq * 4 + r] = s2[r];
        }
    }
    __syncthreads();

    if (doLN) {
#pragma unroll
        for (int r = 0; r < 4; r++) {
            int i = lq * 4 + r;
            int row = bm + i;
            float sm = rs[0][i] + rs[1][i] + rs[2][i] + rs[3][i]
                     + rs[4][i] + rs[5][i] + rs[6][i] + rs[7][i];
            float sq = qs[0][i] + qs[1][i] + qs[2][i] + qs[3][i]
                     + qs[4][i] + qs[5][i] + qs[6][i] + qs[7][i];
            float mean = sm * (1.0f / DD);
            float var  = sq * (1.0f / DD) - mean * mean;
            float rstd = rsqrtf(var + 1e-5f);
#pragma unroll
            for (int nt = 0; nt < 2; nt++) {
                int col = wid * 32 + nt * 16 + lm;
                lnout[(size_t)row * DD + col] =
                    f2bf((val[r][nt] - mean) * rstd * g[col] + bb[col]);
            }
        }
    }

    // ---- Fused head (last layer, block owning row TT-1 of this batch).
    if (doHead && tb == 63) {
        const int i15 = 15;
        float sm = rs[0][i15] + rs[1][i15] + rs[2][i15] + rs[3][i15]
                 + rs[4][i15] + rs[5][i15] + rs[6][i15] + rs[7][i15];
        float sq = qs[0][i15] + qs[1][i15] + qs[2][i15] + qs[3][i15]
                 + qs[4][i15] + qs[5][i15] + qs[6][i15] + qs[7][i15];
        float mean = sm * (1.0f / DD);
        float var  = sq * (1.0f / DD) - mean * mean;
        float rstd = rsqrtf(var + 1e-5f);
        const size_t row = (size_t)bm + 15;          // = b*TT + (TT-1)

        if (tid < DD) {
            float v = h[row * DD + tid];             // written by this block above
            hn[tid] = (v - mean) * rstd * g[tid] + bb[tid];
        }
        __syncthreads();

        if (tid < DD) {
            float a1 = b1h[tid];
            const float* w1r = w1h + tid * DD;
#pragma unroll 8
            for (int k = 0; k < DD; k++) a1 = fmaf(hn[k], w1r[k], a1);
            sl1[tid] = a1 / (1.0f + __expf(-a1));
        }
        __syncthreads();

        if (tid < OUT_LEN) {
            float a2 = b2h[tid];
            const float* w2r = w2h + tid * DD;
#pragma unroll 8
            for (int k = 0; k < DD; k++) a2 = fmaf(sl1[k], w2r[k], a2);
            outp[b * OUT_LEN + tid] = a2;
        }
    }
}

// ---------------------------------------------------------------------------
extern "C" void kernel_launch(void* const* d_in, const int* in_sizes, int n_in,
                              void* d_out, int out_size, void* d_ws, size_t ws_size,
                              hipStream_t stream)
{
    (void)in_sizes; (void)n_in; (void)out_size; (void)ws_size;

    const float* x       = (const float*)d_in[0];
    const float* emb_w   = (const float*)d_in[1];
    const float* emb_b   = (const float*)d_in[2];
    const float* norm_g  = (const float*)d_in[3];
    const float* norm_b  = (const float*)d_in[4];
    const float* in_w    = (const float*)d_in[5];
    const float* conv_w  = (const float*)d_in[6];
    const float* A_p     = (const float*)d_in[7];
    const float* D_p     = (const float*)d_in[8];
    const float* dt1_w   = (const float*)d_in[9];
    const float* dt1_b   = (const float*)d_in[10];
    const float* dt2_w   = (const float*)d_in[11];
    const float* dt2_b   = (const float*)d_in[12];
    const float* out_w   = (const float*)d_in[13];
    const float* final_g = (const float*)d_in[14];
    const float* final_b = (const float*)d_in[15];
    const float* head1_w = (const float*)d_in[16];
    const float* head1_b = (const float*)d_in[17];
    const float* head2_w = (const float*)d_in[18];
    const float* head2_b = (const float*)d_in[19];
    float* outp = (float*)d_out;

    char* ws = (char*)d_ws;
    float* h     = (float*)ws;                ws += (size_t)MM * DD * 4;   // fp32 residual
    u16*   vbf   = (u16*)ws;                  ws += (size_t)MM * HH * 2;   // gemm1 out
    u16*   vsb   = (u16*)ws;                  ws += (size_t)MM * HH * 2;   // conv+silu
    u16*   lnbuf = (u16*)ws;                  ws += (size_t)MM * DD * 2;   // LN out
    float* dtr   = (float*)ws;                ws += (size_t)MM * RR * 4;
    u16*   Lst   = (u16*)ws;                  ws += (size_t)CC * BB * HH * NN * 2;  // bf16
    float* sdt   = (float*)ws;                ws += (size_t)CC * BB * HH * 4;
    u16*   wbf_in  = (u16*)ws;                ws += (size_t)4 * HH * DD * 2;
    u16*   wbf_out = (u16*)ws;                ws += (size_t)4 * DD * HH * 2;

    const int NW = 4 * HH * DD;
    embed_ln_cvt_kernel<<<MM + (2 * NW) / 256, 256, 0, stream>>>(
        x, emb_w, emb_b, norm_g, norm_b, h, lnbuf,
        in_w, wbf_in, out_w, wbf_out, NW);

    for (int l = 0; l < 4; l++) {
        gemm_bf16<128, 64, 1><<<dim3(HH / 64, MM / 128), 256, 0, stream>>>(
            lnbuf, wbf_in + (size_t)l * HH * DD, vbf, MM, HH, DD, 0);

        conv_scan1<<<dim3(CC, BB), 512, 0, stream>>>(
            vbf, conv_w + (size_t)l * HH * 3,
            dt1_w + (size_t)l * RR * HH, dt1_b + l * RR,
            dt2_w + (size_t)l * HH * RR, dt2_b + l * HH,
            A_p + (size_t)l * HH * NN,
            vsb, dtr, Lst, sdt);

        scan_carry_par<<<(BB * HH) / 4, 256, 0, stream>>>(
            A_p + (size_t)l * HH * NN, sdt, Lst);

        const float* g_next = (l < 3) ? (norm_g + (l + 1) * DD) : final_g;
        const float* b_next = (l < 3) ? (norm_b + (l + 1) * DD) : final_b;
        scan2_gemm2_ln<<<MM / 16, 512, 0, stream>>>(
            vsb, dtr, dt2_w + (size_t)l * HH * RR, dt2_b + l * HH,
            A_p + (size_t)l * HH * NN, D_p + l * HH,
            Lst, wbf_out + (size_t)l * DD * HH,
            h, g_next, b_next, lnbuf, (l < 3) ? 1 : 0,
            head1_w, head1_b, head2_w, head2_b, outp, (l == 3) ? 1 : 0);
    }
}

// Round 14
// 453.074 us; speedup vs baseline: 1.0574x; 1.0574x over previous
//
#include <hip/hip_runtime.h>
#include <hip/hip_bf16.h>
#include <math.h>

// Model dims
#define BB 8
#define TT 1024
#define DD 256
#define HH 512
#define NN 16
#define RR 8
#define OUT_LEN 96
#define IN_DIM 32
#define MM (BB*TT)   // 8192 rows

// scan chunking: SC=16 -> CC=64
#define SC 16
#define CC (TT/SC)   // 64

typedef unsigned short u16;
typedef unsigned int u32;
typedef __attribute__((ext_vector_type(8))) short short8;
typedef __attribute__((ext_vector_type(8))) unsigned short u16x8;
typedef __attribute__((ext_vector_type(4))) float float4v;

__device__ __forceinline__ u16 f2bf(float f) {
    __hip_bfloat16 h = __float2bfloat16(f);
    return *(u16*)&h;
}
__device__ __forceinline__ float bf2f(u16 u) {
    u32 v = ((u32)u) << 16;
    return *(float*)&v;
}

#define GLD_LDS16(src, dst) __builtin_amdgcn_global_load_lds( \
    (const __attribute__((address_space(1))) void*)(src),     \
    (__attribute__((address_space(3))) void*)(dst), 16, 0, 0)

// Raw barrier + counted vmcnt (T4).
#define SBAR()   asm volatile("s_barrier" ::: "memory")
#define VMCNT0() asm volatile("s_waitcnt vmcnt(0)" ::: "memory")
#define VMCNT4() asm volatile("s_waitcnt vmcnt(4)" ::: "memory")
#define VMCNT6() asm volatile("s_waitcnt vmcnt(6)" ::: "memory")
#define VMCNT8() asm volatile("s_waitcnt vmcnt(8)" ::: "memory")

// ---------------------------------------------------------------------------
// Embedding + PE + layer-0 LN (blocks 0..MM-1)  |  weight bf16 cvt (rest).
// ---------------------------------------------------------------------------
__global__ __launch_bounds__(256) void embed_ln_cvt_kernel(
    const float* __restrict__ x, const float* __restrict__ emb_w,
    const float* __restrict__ emb_b,
    const float* __restrict__ g, const float* __restrict__ b,
    float* __restrict__ h, u16* __restrict__ lnout,
    const float* __restrict__ w_in, u16* __restrict__ wbf_in,
    const float* __restrict__ w_out, u16* __restrict__ wbf_out, int nw)
{
    int bid = blockIdx.x;
    if (bid >= MM) {
        int i = (bid - MM) * 256 + threadIdx.x;
        if (i < nw) wbf_in[i] = f2bf(w_in[i]);
        else        wbf_out[i - nw] = f2bf(w_out[i - nw]);
        return;
    }

    int bt = bid;
    int d  = threadIdx.x;
    int t  = bt & (TT - 1);

    __shared__ float xs[IN_DIM];
    __shared__ float red[4], red2[4];
    if (threadIdx.x < IN_DIM) xs[threadIdx.x] = x[bt * IN_DIM + threadIdx.x];
    __syncthreads();

    const float* w = emb_w + d * IN_DIM;
    float acc = emb_b[d];
#pragma unroll
    for (int i = 0; i < IN_DIM; i++) acc = fmaf(xs[i], w[i], acc);

    int i2 = d & ~1;
    float div = __expf(-(float)i2 * 0.0359778918f);   // ln(10000)/256
    float arg = (float)t * div;
    float pe = (d & 1) ? __cosf(arg) : __sinf(arg);
    float val = acc + pe;
    h[bt * DD + d] = val;

    float s = val;
#pragma unroll
    for (int o = 32; o > 0; o >>= 1) s += __shfl_down(s, o);
    int lane = d & 63, wave = d >> 6;
    if (lane == 0) red[wave] = s;
    __syncthreads();
    float mean = (red[0] + red[1] + red[2] + red[3]) * (1.0f / DD);

    float c = val - mean;
    float s2 = c * c;
#pragma unroll
    for (int o = 32; o > 0; o >>= 1) s2 += __shfl_down(s2, o);
    if (lane == 0) red2[wave] = s2;
    __syncthreads();
    float var = (red2[0] + red2[1] + red2[2] + red2[3]) * (1.0f / DD);

    lnout[bt * DD + d] = f2bf(c * rsqrtf(var + 1e-5f) * g[d] + b[d]);
}

// ---------------------------------------------------------------------------
// bf16 MFMA NT GEMM, 128x64, BK=64, dbuf + counted-vmcnt (R7/R8-validated).
// ---------------------------------------------------------------------------
template<int BM, int BN, int OUT_BF16>
__global__ __launch_bounds__(256) void gemm_bf16(
    const u16* __restrict__ A, const u16* __restrict__ B,
    void* __restrict__ Cv, int M, int N, int K, int addC)
{
    constexpr int BK = 64;
    constexpr int MT = BM / 32;
    constexpr int NT = BN / 32;
    static_assert(BM == 128 && BN == 64, "vmcnt count assumes 6 loads/thread");

    __shared__ __align__(16) u16 Al[2][8][BM][8];
    __shared__ __align__(16) u16 Bl[2][8][BN][8];

    const int tid = threadIdx.x;
    const int bm = blockIdx.y * BM;
    const int bn = blockIdx.x * BN;
    const int wid = tid >> 6, lane = tid & 63;
    const int wm = wid >> 1, wn = wid & 1;
    const int lq = lane >> 4, lm = lane & 15;

    float4v acc[MT][NT];
#pragma unroll
    for (int i = 0; i < MT; i++)
#pragma unroll
        for (int j = 0; j < NT; j++) acc[i][j] = (float4v){0.f, 0.f, 0.f, 0.f};

#pragma unroll
    for (int it = 0; it < (8 * BM) / 256; it++) {
        int c = it * 256 + tid;
        int q = c / BM, row = c % BM;
        GLD_LDS16(A + (size_t)(bm + row) * K + q * 8, &Al[0][q][row][0]);
    }
#pragma unroll
    for (int it = 0; it < (8 * BN) / 256; it++) {
        int c = it * 256 + tid;
        int q = c / BN, row = c % BN;
        GLD_LDS16(B + (size_t)(bn + row) * K + q * 8, &Bl[0][q][row][0]);
    }

    const int nt = K / BK;
    int cur = 0;
    for (int i = 0; i < nt; i++) {
        if (i + 1 < nt) {
            int nxt = cur ^ 1;
            int k1 = (i + 1) * BK;
#pragma unroll
            for (int it = 0; it < (8 * BM) / 256; it++) {
                int c = it * 256 + tid;
                int q = c / BM, row = c % BM;
                GLD_LDS16(A + (size_t)(bm + row) * K + k1 + q * 8, &Al[nxt][q][row][0]);
            }
#pragma unroll
            for (int it = 0; it < (8 * BN) / 256; it++) {
                int c = it * 256 + tid;
                int q = c / BN, row = c % BN;
                GLD_LDS16(B + (size_t)(bn + row) * K + k1 + q * 8, &Bl[nxt][q][row][0]);
            }
            VMCNT6();
        } else {
            VMCNT0();
        }
        SBAR();

        short8 af[2][MT], bf[2][NT];
#pragma unroll
        for (int kk = 0; kk < 2; kk++) {
#pragma unroll
            for (int mt = 0; mt < MT; mt++)
                af[kk][mt] = *(const short8*)&Al[cur][kk * 4 + lq][wm * (BM / 2) + mt * 16 + lm][0];
#pragma unroll
            for (int nt2 = 0; nt2 < NT; nt2++)
                bf[kk][nt2] = *(const short8*)&Bl[cur][kk * 4 + lq][wn * (BN / 2) + nt2 * 16 + lm][0];
        }

#pragma unroll
        for (int kk = 0; kk < 2; kk++)
#pragma unroll
            for (int mt = 0; mt < MT; mt++)
#pragma unroll
                for (int nt2 = 0; nt2 < NT; nt2++)
                    acc[mt][nt2] = __builtin_amdgcn_mfma_f32_16x16x32_bf16(
                        af[kk][mt], bf[kk][nt2], acc[mt][nt2], 0, 0, 0);
        SBAR();
        cur ^= 1;
    }

#pragma unroll
    for (int mt = 0; mt < MT; mt++)
#pragma unroll
        for (int nt2 = 0; nt2 < NT; nt2++) {
            int row0 = bm + wm * (BM / 2) + mt * 16 + lq * 4;
            int col  = bn + wn * (BN / 2) + nt2 * 16 + lm;
#pragma unroll
            for (int r = 0; r < 4; r++) {
                float vv = acc[mt][nt2][r];
                if (OUT_BF16) {
                    ((u16*)Cv)[(size_t)(row0 + r) * N + col] = f2bf(vv);
                } else {
                    float* cp = (float*)Cv + (size_t)(row0 + r) * N + col;
                    if (addC) vv += *cp;
                    *cp = vv;
                }
            }
        }
}

// ---------------------------------------------------------------------------
__device__ __forceinline__ float softplus_f(float s) {
    return (s > 20.0f) ? s : __logf(1.0f + __expf(s));
}

// ---------------------------------------------------------------------------
// Fused conv+SiLU+dt1 + chunk-local scan (pass 1). R7/R8-validated.
// R24: local scan now ALSO emits y_intra = Dp*x + sum_n Ap[n]*st_local[n]
// (17 extra fma/t) into ybf -- enables the carry-correction pass 2.
// ---------------------------------------------------------------------------
__global__ __launch_bounds__(512, 4) void conv_scan1(
    const u16* __restrict__ vbf, const float* __restrict__ cwg,
    const float* __restrict__ w1g, const float* __restrict__ b1g,
    const float* __restrict__ dt2_w, const float* __restrict__ dt2_b,
    const float* __restrict__ A_p, const float* __restrict__ D_p,
    u16* __restrict__ vsb, float* __restrict__ dtr,
    u16* __restrict__ Lst, float* __restrict__ sdt,
    u16* __restrict__ ybf)
{
    const int c = blockIdx.x;
    const int b = blockIdx.y;
    const int tid = threadIdx.x;
    const int wave = tid >> 6, lane = tid & 63;
    const int h0 = lane * 8;

    __shared__ float w1s[RR * 2 * 256];       // 16 KB dt1 weights
    __shared__ u16   a_lds[SC][HH];           // 16 KB conv+silu output (bf16)
    __shared__ float ds[SC * RR];             // 512 B dt1 output per row

#pragma unroll
    for (int i = 0; i < 2; i++) {
        int rci = wave + i * 8;               // 0..15
        int r = rci >> 1, jc = rci & 1;
        float4 wv = *(const float4*)(w1g + r * HH + lane * 8 + jc * 4);
        *(float4*)&w1s[rci * 256 + lane * 4] = wv;
    }
    __syncthreads();

    const float* wp = cwg + h0 * 3;
#pragma unroll
    for (int i = 0; i < 2; i++) {
        int tr = wave + i * 8;                // 0..15
        int t  = c * SC + tr;
        size_t m = (size_t)b * TT + t;

        const u16* vrow = vbf + m * HH + h0;
        u16x8 x0 = *(const u16x8*)vrow;
        u16x8 xm = (t > 0)      ? *(const u16x8*)(vrow - HH) : (u16x8)(0);
        u16x8 xp = (t < TT - 1) ? *(const u16x8*)(vrow + HH) : (u16x8)(0);

        float a[8];
        u16x8 o;
#pragma unroll
        for (int j = 0; j < 8; j++) {
            float s = wp[j * 3] * bf2f(xm[j]);
            s = fmaf(wp[j * 3 + 1], bf2f(x0[j]), s);
            s = fmaf(wp[j * 3 + 2], bf2f(xp[j]), s);
            s = s / (1.0f + __expf(-s));
            a[j] = s;
            o[j] = f2bf(s);
        }
        *(u16x8*)(vsb + m * HH + h0) = o;       // kept (cheap; debug/partial reuse)
        *(u16x8*)&a_lds[tr][h0]      = o;       // for local scan (same bf16)

        float acc[RR];
#pragma unroll
        for (int r = 0; r < RR; r++) {
            float4 wlo = *(const float4*)&w1s[(r * 2 + 0) * 256 + lane * 4];
            float4 whi = *(const float4*)&w1s[(r * 2 + 1) * 256 + lane * 4];
            float s = a[0] * wlo.x;
            s = fmaf(a[1], wlo.y, s);
            s = fmaf(a[2], wlo.z, s);
            s = fmaf(a[3], wlo.w, s);
            s = fmaf(a[4], whi.x, s);
            s = fmaf(a[5], whi.y, s);
            s = fmaf(a[6], whi.z, s);
            s = fmaf(a[7], whi.w, s);
            acc[r] = s;
        }
#pragma unroll
        for (int r = 0; r < RR; r++) {
#pragma unroll
            for (int o2 = 1; o2 < 64; o2 <<= 1) acc[r] += __shfl_xor(acc[r], o2);
        }
        if (lane == 0) {
#pragma unroll
            for (int r = 0; r < RR; r++) acc[r] = fmaxf(acc[r] + b1g[r], 0.0f);
            *(float4*)(dtr + m * RR)     = make_float4(acc[0], acc[1], acc[2], acc[3]);
            *(float4*)(dtr + m * RR + 4) = make_float4(acc[4], acc[5], acc[6], acc[7]);
#pragma unroll
            for (int r = 0; r < RR; r++) ds[tr * RR + r] = acc[r];
        }
    }
    __syncthreads();

    const int h = tid;
    float A2[NN], invA[NN], Apr[NN], st[NN];
    const float* ap = A_p + h * NN;
#pragma unroll
    for (int n = 0; n < NN; n++) {
        float apv = ap[n];
        Apr[n] = apv;
        float av = -__expf(apv);
        A2[n] = av * 1.44269504f;
        invA[n] = 1.0f / av;
        st[n] = 0.0f;
    }
    float w2[RR];
#pragma unroll
    for (int r = 0; r < RR; r++) w2[r] = dt2_w[h * RR + r];
    float b2 = dt2_b[h];
    float Dp = D_p[h];

    u16* ybase = ybf + ((size_t)b * TT + (size_t)c * SC) * HH + h;

    float xv = bf2f(a_lds[0][h]);
    float s_dt = 0.0f;
#pragma unroll 2
    for (int t = 0; t < SC; t++) {
        float xn = (t + 1 < SC) ? bf2f(a_lds[t + 1][h]) : 0.0f;
        float s = b2;
#pragma unroll
        for (int r = 0; r < RR; r++) s = fmaf(ds[t * RR + r], w2[r], s);
        float dt = softplus_f(s);
        s_dt += dt;
        float dtx = dt * xv;
        float accY = Dp * xv;
#pragma unroll
        for (int n = 0; n < NN; n++) {
            float e = __builtin_amdgcn_exp2f(A2[n] * dt);
            float u = invA[n] * dtx;
            st[n] = fmaf(e, st[n] + u, -u);
            accY = fmaf(st[n], Apr[n], accY);
        }
        ybase[(size_t)t * HH] = f2bf(accY);     // y_intra (local-state output)
        xv = xn;
    }

    size_t base = (((size_t)c * BB + b) * HH + h) * NN;
    u16x8 lo, hi;
#pragma unroll
    for (int n = 0; n < 8; n++) { lo[n] = f2bf(st[n]); hi[n] = f2bf(st[n + 8]); }
    *(u16x8*)(Lst + base)     = lo;
    *(u16x8*)(Lst + base + 8) = hi;
    sdt[((size_t)c * BB + b) * HH + h] = s_dt;
}

// ---------------------------------------------------------------------------
// Wave-parallel carry (R3/R5/R7-validated). One wave per (b,h); lane = chunk.
// ---------------------------------------------------------------------------
__global__ __launch_bounds__(256) void scan_carry_par(
    const float* __restrict__ A_p, const float* __restrict__ sdt,
    u16* __restrict__ Lst)
{
    int gw   = (blockIdx.x << 2) | (threadIdx.x >> 6);
    int lane = threadIdx.x & 63;
    int b = gw >> 9;
    int h = gw & 511;

    size_t sidx = ((size_t)lane * BB + b) * HH + h;
    float sd = sdt[sidx];
    const float* ap = A_p + h * NN;
    u16x8 Llo = *(const u16x8*)(Lst + sidx * NN);
    u16x8 Lhi = *(const u16x8*)(Lst + sidx * NN + 8);
    u16x8 Elo, Ehi;
#pragma unroll
    for (int n = 0; n < NN; n++) {
        float An = -__expf(ap[n]);
        float p  = __expf(An * sd);
        float lv = bf2f((n < 8) ? Llo[n] : Lhi[n - 8]);
#pragma unroll
        for (int d2 = 1; d2 < 64; d2 <<= 1) {
            float pp = __shfl_up(p, d2);
            float pl = __shfl_up(lv, d2);
            if (lane >= d2) { lv = fmaf(pl, p, lv); p = pp * p; }
        }
        float E = __shfl_up(lv, 1);
        if (lane == 0) E = 0.0f;
        if (n < 8) Elo[n] = f2bf(E); else Ehi[n - 8] = f2bf(E);
    }
    *(u16x8*)(Lst + sidx * NN)     = Elo;
    *(u16x8*)(Lst + sidx * NN + 8) = Ehi;
}

// ---------------------------------------------------------------------------
// R10 geometry (champion, 467.9us) + R24 Phase-S rewrite: carry-correction.
// Chunked-scan identity: st_t = st_t^local + P_t*carry, P_t[n]=exp(A[n]*cd_t)
// => y_t = y_t^intra + sum_n (Ap[n]*carry[n]) * exp2(A2[n]*cd_t).
// Phase S now: recompute dt (cheap), cd += dt, 16 exp2 + 16 fma correction,
// add y_intra (from ybf). No state recurrence, no invA/Dp, no vsb reads.
// Phase G / epilogue / head verbatim from R10.
// ---------------------------------------------------------------------------
__global__ __launch_bounds__(512) void scan2_gemm2_ln(
    const u16* __restrict__ ybf, const float* __restrict__ dtr,
    const float* __restrict__ dt2_w, const float* __restrict__ dt2_b,
    const float* __restrict__ A_p,
    const u16* __restrict__ carry,          // Lst (exclusive chunk prefixes)
    const u16* __restrict__ B,              // out_w bf16 [256][512]
    float* __restrict__ h,
    const float* __restrict__ g, const float* __restrict__ bb,
    u16* __restrict__ lnout, int doLN,
    const float* __restrict__ w1h, const float* __restrict__ b1h,
    const float* __restrict__ w2h, const float* __restrict__ b2h,
    float* __restrict__ outp, int doHead)
{
    const int bid = blockIdx.x;          // 0..255
    const int b   = bid >> 5;
    const int tb  = bid & 31;
    const int t0  = tb * 32;
    const int c0  = tb * 2;
    const int bm  = bid * 32;            // global row base (b*TT + t0)

    const int tid = threadIdx.x;         // 0..511
    const int wid = tid >> 6;
    const int lane = tid & 63;
    const int lq = lane >> 4, lm = lane & 15;
    const int wm = wid >> 2;             // 0..1: row half
    const int wn = wid & 3;              // 0..3: 64-col stripe

    __shared__ __align__(16) u16 Yl[32 * 512];        // 32 KB swizzled y
    __shared__ __align__(16) u16 Bl[3][8][256][8];    // 96 KB (3-deep, R10)
    __shared__ float ds[32 * RR];                      // 1 KB
    __shared__ float rs[4][32], qs[4][32];
    __shared__ float hn[DD], sl1[DD];                  // head scratch (2 KB)

    // issue B K-tiles 0 AND 1 -- both hide under the scan phase
#pragma unroll
    for (int pt = 0; pt < 2; pt++) {
#pragma unroll
        for (int it = 0; it < 4; it++) {
            int cth = it * 512 + tid;
            int q = cth >> 8, row = cth & 255;
            GLD_LDS16(B + (size_t)row * 512 + pt * 64 + q * 8, &Bl[pt][q][row][0]);
        }
    }

    const int hh = tid;

    // carry vectors -> K[n] = Ap[n]*carry[n]
    float K0[NN], K1[NN];
    float A2[NN];
    {
        size_t cb0 = (((size_t)(c0 + 0) * BB + b) * HH + hh) * NN;
        size_t cb1 = (((size_t)(c0 + 1) * BB + b) * HH + hh) * NN;
        u16x8 l0 = *(const u16x8*)(carry + cb0);
        u16x8 h0 = *(const u16x8*)(carry + cb0 + 8);
        u16x8 l1 = *(const u16x8*)(carry + cb1);
        u16x8 h1 = *(const u16x8*)(carry + cb1 + 8);
        const float* ap = A_p + hh * NN;
#pragma unroll
        for (int n = 0; n < NN; n++) {
            float apv = ap[n];
            float av = -__expf(apv);
            A2[n] = av * 1.44269504f;
            float c0v = bf2f((n < 8) ? l0[n] : h0[n - 8]);
            float c1v = bf2f((n < 8) ? l1[n] : h1[n - 8]);
            K0[n] = apv * c0v;
            K1[n] = apv * c1v;
        }
    }

    // stage dt rows for both chunks
    if (tid < 256) {
        int tr = tid >> 3, r = tid & 7;
        ds[tid] = dtr[((size_t)b * TT + t0 + tr) * RR + r];
    }

    float w2[RR];
#pragma unroll
    for (int r = 0; r < RR; r++) w2[r] = dt2_w[hh * RR + r];
    float b2 = dt2_b[hh];
    __syncthreads();   // ds ready

    // ---- Phase S: dual-chunk carry correction (no state recurrence)
    const u16* yb0 = ybf + ((size_t)b * TT + (size_t)(c0 + 0) * SC) * HH + hh;
    const u16* yb1 = ybf + ((size_t)b * TT + (size_t)(c0 + 1) * SC) * HH + hh;
    float cd0 = 0.0f, cd1 = 0.0f;
#pragma unroll
    for (int t = 0; t < SC; t++) {
        float s0 = b2, s1 = b2;
#pragma unroll
        for (int r = 0; r < RR; r++) {
            s0 = fmaf(ds[t * RR + r], w2[r], s0);
            s1 = fmaf(ds[(SC + t) * RR + r], w2[r], s1);
        }
        cd0 += softplus_f(s0);
        cd1 += softplus_f(s1);
        float yl0 = bf2f(yb0[(size_t)t * HH]);
        float yl1 = bf2f(yb1[(size_t)t * HH]);
        float corr0 = 0.0f, corr1 = 0.0f;
#pragma unroll
        for (int n = 0; n < NN; n++) {
            corr0 = fmaf(K0[n], __builtin_amdgcn_exp2f(A2[n] * cd0), corr0);
            corr1 = fmaf(K1[n], __builtin_amdgcn_exp2f(A2[n] * cd1), corr1);
        }
        Yl[t * 512 + (hh ^ ((t & 7) << 3))] = f2bf(yl0 + corr0);
        int tr1 = SC + t;
        Yl[tr1 * 512 + (hh ^ ((tr1 & 7) << 3))] = f2bf(yl1 + corr1);
    }
    __syncthreads();   // Yl complete; drains vmem (tiles 0,1 landed)

    // ---- Phase G: C[32x256] = Y[32x512] @ B[256x512]^T (3-deep pipeline)
    float4v acc4[4];
#pragma unroll
    for (int j = 0; j < 4; j++) acc4[j] = (float4v){0.f, 0.f, 0.f, 0.f};

    for (int i = 0; i < 8; i++) {
        if (i + 2 < 8) {
            int nb = (i + 2) % 3;               // freed at step i-1
            int k1 = (i + 2) * 64;
#pragma unroll
            for (int it = 0; it < 4; it++) {
                int cth = it * 512 + tid;
                int q = cth >> 8, row = cth & 255;
                GLD_LDS16(B + (size_t)row * 512 + k1 + q * 8, &Bl[nb][q][row][0]);
            }
            VMCNT8();                            // tile i landed; i+1,i+2 in flight
        } else if (i + 1 < 8) {
            VMCNT4();                            // tile i landed; i+1 in flight
        } else {
            VMCNT0();
        }
        SBAR();

        int cur = i % 3;
        int k0 = i * 64;
        short8 af[2], bf[2][4];
#pragma unroll
        for (int kk = 0; kk < 2; kk++) {
            int row = wm * 16 + lm;
            int kg  = (k0 >> 3) + kk * 4 + lq;           // k-group of 8
            af[kk] = *(const short8*)&Yl[row * 512 + ((kg ^ (row & 7)) << 3)];
#pragma unroll
            for (int nt = 0; nt < 4; nt++)
                bf[kk][nt] = *(const short8*)&Bl[cur][kk * 4 + lq][wn * 64 + nt * 16 + lm][0];
        }
#pragma unroll
        for (int kk = 0; kk < 2; kk++)
#pragma unroll
            for (int nt = 0; nt < 4; nt++)
                acc4[nt] = __builtin_amdgcn_mfma_f32_16x16x32_bf16(
                    af[kk], bf[kk][nt], acc4[nt], 0, 0, 0);
        SBAR();
    }

    // ---- Epilogue: residual + stats + LN
    float val[4][4];
    float s1[4] = {0.f, 0.f, 0.f, 0.f}, s2[4] = {0.f, 0.f, 0.f, 0.f};
#pragma unroll
    for (int r = 0; r < 4; r++) {
        int row = bm + wm * 16 + lq * 4 + r;
#pragma unroll
        for (int nt = 0; nt < 4; nt++) {
            int col = wn * 64 + nt * 16 + lm;
            float v = acc4[nt][r] + h[(size_t)row * DD + col];
            val[r][nt] = v;
            s1[r] += v;
            s2[r] = fmaf(v, v, s2[r]);
            h[(size_t)row * DD + col] = v;
        }
    }
#pragma unroll
    for (int r = 0; r < 4; r++) {
#pragma unroll
        for (int o = 1; o < 16; o <<= 1) {
            s1[r] += __shfl_xor(s1[r], o);
            s2[r] += __shfl_xor(s2[r], o);
        }
    }
    if (lm == 0) {
#pragma unroll
        for (int r = 0; r < 4; r++) {
            rs[wn][wm * 16 + lq * 4 + r] = s1[r];
            qs[wn][wm * 16 + lq * 4 + r] = s2[r];
        }
    }
    __syncthreads();

    if (doLN) {
#pragma unroll
        for (int r = 0; r < 4; r++) {
            int i = wm * 16 + lq * 4 + r;
            int row = bm + i;
            float mean = (rs[0][i] + rs[1][i] + rs[2][i] + rs[3][i]) * (1.0f / DD);
            float var  = (qs[0][i] + qs[1][i] + qs[2][i] + qs[3][i]) * (1.0f / DD) - mean * mean;
            float rstd = rsqrtf(var + 1e-5f);
#pragma unroll
            for (int nt = 0; nt < 4; nt++) {
                int col = wn * 64 + nt * 16 + lm;
                lnout[(size_t)row * DD + col] =
                    f2bf((val[r][nt] - mean) * rstd * g[col] + bb[col]);
            }
        }
    }

    // ---- Fused head (last layer, block owning row TT-1 of this batch).
    if (doHead && tb == 31) {
        const int i31 = 31;
        float mean = (rs[0][i31] + rs[1][i31] + rs[2][i31] + rs[3][i31]) * (1.0f / DD);
        float var  = (qs[0][i31] + qs[1][i31] + qs[2][i31] + qs[3][i31]) * (1.0f / DD) - mean * mean;
        float rstd = rsqrtf(var + 1e-5f);
        const size_t row = (size_t)bm + 31;          // = b*TT + (TT-1)

        if (tid < DD) {
            float v = h[row * DD + tid];             // written by this block above
            hn[tid] = (v - mean) * rstd * g[tid] + bb[tid];
        }
        __syncthreads();

        if (tid < DD) {
            float a1 = b1h[tid];
            const float* w1r = w1h + tid * DD;
#pragma unroll 8
            for (int k = 0; k < DD; k++) a1 = fmaf(hn[k], w1r[k], a1);
            sl1[tid] = a1 / (1.0f + __expf(-a1));
        }
        __syncthreads();

        if (tid < OUT_LEN) {
            float a2 = b2h[tid];
            const float* w2r = w2h + tid * DD;
#pragma unroll 8
            for (int k = 0; k < DD; k++) a2 = fmaf(sl1[k], w2r[k], a2);
            outp[b * OUT_LEN + tid] = a2;
        }
    }
}

// ---------------------------------------------------------------------------
extern "C" void kernel_launch(void* const* d_in, const int* in_sizes, int n_in,
                              void* d_out, int out_size, void* d_ws, size_t ws_size,
                              hipStream_t stream)
{
    (void)in_sizes; (void)n_in; (void)out_size; (void)ws_size;

    const float* x       = (const float*)d_in[0];
    const float* emb_w   = (const float*)d_in[1];
    const float* emb_b   = (const float*)d_in[2];
    const float* norm_g  = (const float*)d_in[3];
    const float* norm_b  = (const float*)d_in[4];
    const float* in_w    = (const float*)d_in[5];
    const float* conv_w  = (const float*)d_in[6];
    const float* A_p     = (const float*)d_in[7];
    const float* D_p     = (const float*)d_in[8];
    const float* dt1_w   = (const float*)d_in[9];
    const float* dt1_b   = (const float*)d_in[10];
    const float* dt2_w   = (const float*)d_in[11];
    const float* dt2_b   = (const float*)d_in[12];
    const float* out_w   = (const float*)d_in[13];
    const float* final_g = (const float*)d_in[14];
    const float* final_b = (const float*)d_in[15];
    const float* head1_w = (const float*)d_in[16];
    const float* head1_b = (const float*)d_in[17];
    const float* head2_w = (const float*)d_in[18];
    const float* head2_b = (const float*)d_in[19];
    float* outp = (float*)d_out;

    char* ws = (char*)d_ws;
    float* h     = (float*)ws;                ws += (size_t)MM * DD * 4;   // fp32 residual
    u16*   vbf   = (u16*)ws;                  ws += (size_t)MM * HH * 2;   // gemm1 out
    u16*   vsb   = (u16*)ws;                  ws += (size_t)MM * HH * 2;   // conv+silu
    u16*   ybf   = (u16*)ws;                  ws += (size_t)MM * HH * 2;   // y_intra
    u16*   lnbuf = (u16*)ws;                  ws += (size_t)MM * DD * 2;   // LN out
    float* dtr   = (float*)ws;                ws += (size_t)MM * RR * 4;
    u16*   Lst   = (u16*)ws;                  ws += (size_t)CC * BB * HH * NN * 2;  // bf16
    float* sdt   = (float*)ws;                ws += (size_t)CC * BB * HH * 4;
    u16*   wbf_in  = (u16*)ws;                ws += (size_t)4 * HH * DD * 2;
    u16*   wbf_out = (u16*)ws;                ws += (size_t)4 * DD * HH * 2;

    const int NW = 4 * HH * DD;
    embed_ln_cvt_kernel<<<MM + (2 * NW) / 256, 256, 0, stream>>>(
        x, emb_w, emb_b, norm_g, norm_b, h, lnbuf,
        in_w, wbf_in, out_w, wbf_out, NW);

    for (int l = 0; l < 4; l++) {
        gemm_bf16<128, 64, 1><<<dim3(HH / 64, MM / 128), 256, 0, stream>>>(
            lnbuf, wbf_in + (size_t)l * HH * DD, vbf, MM, HH, DD, 0);

        conv_scan1<<<dim3(CC, BB), 512, 0, stream>>>(
            vbf, conv_w + (size_t)l * HH * 3,
            dt1_w + (size_t)l * RR * HH, dt1_b + l * RR,
            dt2_w + (size_t)l * HH * RR, dt2_b + l * HH,
            A_p + (size_t)l * HH * NN, D_p + l * HH,
            vsb, dtr, Lst, sdt, ybf);

        scan_carry_par<<<(BB * HH) / 4, 256, 0, stream>>>(
            A_p + (size_t)l * HH * NN, sdt, Lst);

        const float* g_next = (l < 3) ? (norm_g + (l + 1) * DD) : final_g;
        const float* b_next = (l < 3) ? (norm_b + (l + 1) * DD) : final_b;
        scan2_gemm2_ln<<<MM / 32, 512, 0, stream>>>(
            ybf, dtr, dt2_w + (size_t)l * HH * RR, dt2_b + l * HH,
            A_p + (size_t)l * HH * NN,
            Lst, wbf_out + (size_t)l * DD * HH,
            h, g_next, b_next, lnbuf, (l < 3) ? 1 : 0,
            head1_w, head1_b, head2_w, head2_b, outp, (l == 3) ? 1 : 0);
    }
}